// Round 3
// baseline (349.356 us; speedup 1.0000x reference)
//
#include <hip/hip_runtime.h>
#include <hip/hip_bf16.h>

#define NTOK 196
#define CDIM 768
#define BSAMP 256
#define NCLS 701
#define NCLSP 704
#define TILE 8
#define NTA 25   // Phase A tiles: 24 full (8 tokens) + 1 tail (4 tokens)

typedef __attribute__((ext_vector_type(8))) short bf16x8;
typedef __attribute__((ext_vector_type(4))) float f32x4;

__device__ __forceinline__ void add4(float4& a, const float4& b) {
  a.x += b.x; a.y += b.y; a.z += b.z; a.w += b.w;
}

// Async global->LDS, 16B per lane. Dest is wave-uniform base + lane*16.
__device__ __forceinline__ void g2l16(const float* g, float* l) {
  __builtin_amdgcn_global_load_lds(
      (const __attribute__((address_space(1))) void*)g,
      (__attribute__((address_space(3))) void*)l, 16, 0, 0);
}

// One block per (sample, branch) task. 512 threads = 8 waves.
// R3: global_load_lds streaming pipeline. R0/R2 showed the register
// allocator pins in-flight loads at ~3 per wave (VGPR 44/56), leaving the
// kernel latency-bound at ~1.3 TB/s HBM. global_load_lds queues loads on
// vmcnt with NO dest VGPRs: tiles of 8 token-rows (24KB) double-buffered in
// LDS, each wave issues exactly 3 dwordx4 loads per tile (tail padded with
// dummy loads so vmcnt immediates stay uniform), counted s_waitcnt vmcnt(3)
// + raw s_barrier (T3/T4 style -- __syncthreads would drain vmcnt(0) and
// kill the prefetch). lgkmcnt(0) before the 2nd barrier closes the
// ds_read-vs-next-DMA-overwrite race.
// Token->wave ownership (t*8+wv, ascending) and the energy shuffle chain are
// identical to R0 => energies/rank/k/list bitwise identical; only Phase C's
// partial grouping differs (covered by bf16 tolerance).
// LDS: buf 48KB (aliased by partS/partT at the end) + ~6KB arrays = 54.2KB
// -> 2 blocks/CU.
__global__ __launch_bounds__(512) void sgm_kernel(const float* __restrict__ x1,
                                                  const float* __restrict__ x2,
                                                  __hip_bfloat16* __restrict__ Vb) {
  const int task = blockIdx.x;
  const int s  = task & 255;
  const int br = task >> 8;
  const float* __restrict__ feats = (br ? x2 : x1) + (size_t)s * (NTOK * CDIM);

  const int tid  = threadIdx.x;
  const int lane = tid & 63;
  const int wv   = tid >> 6;   // 0..7

  __shared__ float buf[2][TILE][CDIM];   // 48 KB tile double-buffer
  __shared__ float dummy[256];           // sink for padding loads
  __shared__ float Msh[NTOK];
  __shared__ float Mn[NTOK];
  __shared__ float sortedv[NTOK];
  __shared__ int   rnk[NTOK];
  __shared__ int   list[NTOK];
  __shared__ float redmin[8], redmax[8];
  __shared__ int   kSh;
  __shared__ int   cntSh;

  // ---------------- Phase A: streamed column-sum + energies ----------------
  float4 acc[3];
  #pragma unroll
  for (int g = 0; g < 3; g++) acc[g] = make_float4(0.f, 0.f, 0.f, 0.f);

  // issue tile t (8 token-rows, 24 instrs; tail tile: 12 real + 12 dummy)
  auto issueA = [&](int t) {
    const int nreal3 = (t < NTA - 1) ? 24 : 12;
    float (*bq)[CDIM] = buf[t & 1];
    #pragma unroll
    for (int ii = 0; ii < 3; ii++) {
      const int i = wv + ii * 8;              // wave-uniform instr id
      if (i < nreal3) {
        const int j = i / 3, g = i % 3;
        g2l16(feats + (size_t)(t * TILE + j) * CDIM + g * 256 + lane * 4,
              &bq[j][g * 256]);
      } else {
        g2l16(feats + lane * 4, dummy);       // keep per-wave count = 3
      }
    }
  };

  issueA(0);
  for (int t = 0; t < NTA; t++) {
    if (t + 1 < NTA) {
      issueA(t + 1);
      asm volatile("s_waitcnt vmcnt(3)" ::: "memory");   // tile t landed
    } else {
      asm volatile("s_waitcnt vmcnt(0)" ::: "memory");
    }
    __builtin_amdgcn_s_barrier();

    const int tok = t * TILE + wv;
    if (tok < NTOK) {
      const float* row = buf[t & 1][wv];
      const float4 r0 = *(const float4*)(row + lane * 4);
      const float4 r1 = *(const float4*)(row + lane * 4 + 256);
      const float4 r2 = *(const float4*)(row + lane * 4 + 512);
      add4(acc[0], r0); add4(acc[1], r1); add4(acc[2], r2);
      float e = ((r0.x + r0.y) + (r0.z + r0.w))
              + ((r1.x + r1.y) + (r1.z + r1.w))
              + ((r2.x + r2.y) + (r2.z + r2.w));
      #pragma unroll
      for (int off = 32; off; off >>= 1) e += __shfl_xor(e, off);
      if (lane == 0) Msh[tok] = e;
    }
    // drain own LDS reads before anyone overwrites this buffer next iter
    asm volatile("s_waitcnt lgkmcnt(0)" ::: "memory");
    __builtin_amdgcn_s_barrier();
  }

  if (tid == 0) cntSh = 0;
  __syncthreads();   // vmcnt already 0 here; no drain cost

  // ---------------- Phase B (unchanged) ----------------
  float vmn = (tid < NTOK) ? Msh[tid] :  1e30f;
  float vmx = (tid < NTOK) ? Msh[tid] : -1e30f;
  #pragma unroll
  for (int off = 32; off; off >>= 1) {
    vmn = fminf(vmn, __shfl_xor(vmn, off));
    vmx = fmaxf(vmx, __shfl_xor(vmx, off));
  }
  if (lane == 0) { redmin[wv] = vmn; redmax[wv] = vmx; }
  __syncthreads();
  float mn = redmin[0], mx = redmax[0];
  #pragma unroll
  for (int i = 1; i < 8; i++) { mn = fminf(mn, redmin[i]); mx = fmaxf(mx, redmax[i]); }
  const float rng = mx - mn;
  if (tid < NTOK) Mn[tid] = (Msh[tid] - mn) / rng;   // exact IEEE div, like ref
  __syncthreads();

  if (tid < NTOK) {
    const float mv = Mn[tid];
    int r = 0;
    for (int u = 0; u < NTOK; u++) {
      const float o = Mn[u];
      r += (o < mv) || (o == mv && u < tid);   // stable argsort tie-break
    }
    sortedv[r] = mv;
    rnk[tid] = r;
  }
  __syncthreads();

  if (tid < 64) {
    float bd = -1.0f; int bj = NTOK;
    for (int j = lane; j < NTOK - 1; j += 64) {
      const float sj = sortedv[j];
      const float d = (sj == 0.0f) ? 0.0f : (sortedv[j + 1] - sj);
      if (d > bd || (d == bd && j < bj)) { bd = d; bj = j; }
    }
    #pragma unroll
    for (int off = 32; off; off >>= 1) {
      const float od = __shfl_xor(bd, off);
      const int   oj = __shfl_xor(bj, off);
      if (od > bd || (od == bd && oj < bj)) { bd = od; bj = oj; }
    }
    if (lane == 0) kSh = bj;   // first-occurrence argmax
  }
  __syncthreads();

  const int k = kSh;
  const bool takeFg = (k <= NTOK / 2);

  // compact the smaller set's token indices (order irrelevant for the sum)
  if (tid < NTOK) {
    const int r = rnk[tid];
    const bool inSet = takeFg ? (r < k) : (r >= k);
    if (inSet) { int p = atomicAdd(&cntSh, 1); list[p] = tid; }
  }
  __syncthreads();
  const int m = cntSh;

  // ---------------- Phase C: streamed subset sum ----------------
  float4 tacc[3];
  #pragma unroll
  for (int g = 0; g < 3; g++) tacc[g] = make_float4(0.f, 0.f, 0.f, 0.f);

  const int nct = (m + TILE - 1) / TILE;

  auto issueC = [&](int t) {
    const int rem = m - t * TILE;
    const int nreal3 = (rem >= TILE ? TILE : rem) * 3;
    float (*bq)[CDIM] = buf[t & 1];
    #pragma unroll
    for (int ii = 0; ii < 3; ii++) {
      const int i = wv + ii * 8;
      if (i < nreal3) {
        const int j = i / 3, g = i % 3;
        const int tok = list[t * TILE + j];
        g2l16(feats + (size_t)tok * CDIM + g * 256 + lane * 4,
              &bq[j][g * 256]);
      } else {
        g2l16(feats + lane * 4, dummy);
      }
    }
  };

  if (nct > 0) issueC(0);
  for (int t = 0; t < nct; t++) {
    if (t + 1 < nct) {
      issueC(t + 1);
      asm volatile("s_waitcnt vmcnt(3)" ::: "memory");
    } else {
      asm volatile("s_waitcnt vmcnt(0)" ::: "memory");
    }
    __builtin_amdgcn_s_barrier();

    const int li = t * TILE + wv;
    if (li < m) {
      const float* row = buf[t & 1][wv];
      const float4 r0 = *(const float4*)(row + lane * 4);
      const float4 r1 = *(const float4*)(row + lane * 4 + 256);
      const float4 r2 = *(const float4*)(row + lane * 4 + 512);
      add4(tacc[0], r0); add4(tacc[1], r1); add4(tacc[2], r2);
    }
    asm volatile("s_waitcnt lgkmcnt(0)" ::: "memory");
    __builtin_amdgcn_s_barrier();
  }

  // ---------------- Combine (partials alias the dead tile buffers) --------
  float (*partS)[CDIM] = (float (*)[CDIM])buf[0];
  float (*partT)[CDIM] = (float (*)[CDIM])buf[1];
  const int base = lane * 4;
  #pragma unroll
  for (int g = 0; g < 3; g++) {
    *(float4*)&partS[wv][base + g * 256] = acc[g];
    *(float4*)&partT[wv][base + g * 256] = tacc[g];
  }
  __syncthreads();

  const float fgc = (float)(k > 1 ? k : 1);
  const float bgc = (float)((NTOK - k) > 1 ? (NTOK - k) : 1);
  const size_t rowFg = (size_t)(2 * br + 1) * BSAMP + s;
  const size_t rowBg = (size_t)(2 * br    ) * BSAMP + s;
  for (int c = tid; c < CDIM; c += 512) {
    float S = 0.0f, T = 0.0f;
    #pragma unroll
    for (int w = 0; w < 8; w++) { S += partS[w][c]; T += partT[w][c]; }
    float fg, bg;
    if (takeFg) { fg = T;     bg = S - T; }
    else        { bg = T;     fg = S - T; }
    Vb[rowFg * CDIM + c] = __float2bfloat16(fg / fgc);
    Vb[rowBg * CDIM + c] = __float2bfloat16(bg / bgc);
  }
}

// W [768][701] fp32 -> WT [704][768] bf16 (rows 701..703 zero-padded).
__global__ __launch_bounds__(256) void wt_kernel(const float* __restrict__ W,
                                                 __hip_bfloat16* __restrict__ WT) {
  __shared__ float tile[32][33];
  const int c0 = blockIdx.x * 32;   // class cols of W
  const int k0 = blockIdx.y * 32;   // k rows of W
  const int tx = threadIdx.x & 31;
  const int ty = threadIdx.x >> 5;  // 0..7
  #pragma unroll
  for (int i = 0; i < 4; i++) {
    const int kr = ty + i * 8;      // 0..31
    const int c = c0 + tx;
    tile[kr][tx] = (c < NCLS) ? W[(size_t)(k0 + kr) * NCLS + c] : 0.0f;
  }
  __syncthreads();
  #pragma unroll
  for (int i = 0; i < 4; i++) {
    const int cr = ty + i * 8;      // class row within tile
    const int cls = c0 + cr;        // < 704 always
    WT[(size_t)cls * CDIM + k0 + tx] = __float2bfloat16(tile[tx][cr]);
  }
}

// Vb [1024][768] bf16 (row-major, K contiguous) x WT [704][768] bf16
// -> out [1024][701] fp32 (+bias). One 16x16 tile per wave via
// mfma_f32_16x16x32_bf16; K-loop fully unrolled (24 MFMA).
// A-frag: lane holds A[m=lane&15][k=(lane>>4)*8 + j]  (16B contiguous)
// B-frag: lane holds B[k=(lane>>4)*8 + j][n=lane&15]  (= WT row, contiguous)
// C/D  : col=lane&15, row=(lane>>4)*4+reg   [m89/m91-verified]
__global__ __launch_bounds__(256) void mfma_gemm(const __hip_bfloat16* __restrict__ Vb,
                                                 const __hip_bfloat16* __restrict__ WT,
                                                 const float* __restrict__ bias,
                                                 float* __restrict__ out) {
  const int w = blockIdx.x * 4 + (threadIdx.x >> 6);   // 0..2815
  const int lane = threadIdx.x & 63;
  const int tr = w / (NCLSP / 16);   // 0..63
  const int tc = w % (NCLSP / 16);   // 0..43
  const int m0 = tr * 16;
  const int n0 = tc * 16;
  const int ko = (lane >> 4) * 8;

  const short* aptr = (const short*)Vb + (size_t)(m0 + (lane & 15)) * CDIM + ko;
  const short* bptr = (const short*)WT + (size_t)(n0 + (lane & 15)) * CDIM + ko;

  f32x4 acc = {0.f, 0.f, 0.f, 0.f};
  #pragma unroll
  for (int k0 = 0; k0 < CDIM; k0 += 32) {
    const bf16x8 af = *(const bf16x8*)(aptr + k0);
    const bf16x8 bf = *(const bf16x8*)(bptr + k0);
    acc = __builtin_amdgcn_mfma_f32_16x16x32_bf16(af, bf, acc, 0, 0, 0);
  }

  const int crow = m0 + (lane >> 4) * 4;
  const int ccol = n0 + (lane & 15);
  if (ccol < NCLS) {
    const float bv = bias[ccol];
    #pragma unroll
    for (int r = 0; r < 4; r++)
      out[(size_t)(crow + r) * NCLS + ccol] = acc[r] + bv;
  }
}

extern "C" void kernel_launch(void* const* d_in, const int* in_sizes, int n_in,
                              void* d_out, int out_size, void* d_ws, size_t ws_size,
                              hipStream_t stream) {
  const float* x1 = (const float*)d_in[0];
  const float* x2 = (const float*)d_in[1];
  const float* W  = (const float*)d_in[2];
  const float* b  = (const float*)d_in[3];
  float* out = (float*)d_out;

  __hip_bfloat16* Vb = (__hip_bfloat16*)d_ws;                       // 1024*768*2 = 1.5 MB
  __hip_bfloat16* WT = (__hip_bfloat16*)((char*)d_ws + 1024 * CDIM * 2); // 704*768*2 = 1.08 MB

  sgm_kernel<<<512, 512, 0, stream>>>(x1, x2, Vb);
  wt_kernel<<<dim3(22, 24), 256, 0, stream>>>(W, WT);
  mfma_gemm<<<704, 256, 0, stream>>>(Vb, WT, b, out);
}